// Round 1
// baseline (385.564 us; speedup 1.0000x reference)
//
#include <hip/hip_runtime.h>
#include <hip/hip_bf16.h>

// GAT attention head, N=8192, F_IN=256, OUT=64, bias_mat [N,N] f32.
// kA: fts = seq@W1 (bf16 MFMA), f1/f2 rank-1 terms, ftsT bf16 for PV B-frags.
// kB: flash-style online softmax over bias stream (256MB HBM = roofline),
//     P kept in A-fragment layout, PV via mfma_f32_16x16x32_bf16.

typedef float f32x4 __attribute__((ext_vector_type(4)));
typedef short bf16x8 __attribute__((ext_vector_type(8)));

__device__ __forceinline__ unsigned short f2bf(float x) {
    union { float f; unsigned u; } v; v.f = x;
    unsigned r = v.u + 0x7FFF + ((v.u >> 16) & 1);   // RNE
    return (unsigned short)(r >> 16);
}

__device__ __forceinline__ float elu1(float x) {
    return x > 0.f ? x : (__expf(x) - 1.f);
}

// ---------------- kernel A: fts, f1, f2, ftsT ----------------
// grid 256, block 256 (4 waves). Block handles 32 q-rows.
// wave w: rg=w&1 (16-row half), oh=w>>1 (32-col half). lane: c=lane&15, g=lane>>4.
__global__ __launch_bounds__(256) void attn_fts(
    const float* __restrict__ seq, const float* __restrict__ W1,
    const float* __restrict__ a1, const float* __restrict__ b1,
    const float* __restrict__ a2, const float* __restrict__ b2,
    unsigned short* __restrict__ ftsT, float* __restrict__ f1g,
    float* __restrict__ f2g)
{
    __shared__ unsigned short w1t[64 * 264];      // W1^T bf16, pad to 264 (528B rows)
    __shared__ unsigned short stage[64 * 40];     // ftsT staging [64 o][32 q +8 pad]
    __shared__ float f1p[2][32];
    __shared__ float f2p[2][32];

    const int tid = threadIdx.x;
    const int qb = blockIdx.x * 32;
    const int w = tid >> 6, rg = w & 1, oh = w >> 1;
    const int lane = tid & 63, c = lane & 15, g = lane >> 4;

    // stage W1^T as bf16 (W1 is [256][64] row-major)
    for (int i = 0; i < 64; ++i) {
        int e = tid + i * 256;            // e = k*64 + o
        int k = e >> 6, o = e & 63;
        w1t[o * 264 + k] = f2bf(W1[e]);
    }
    __syncthreads();

    f32x4 acc[2] = {};                    // acc[ob]: C[16q x 16o]
    const float* srow = seq + (long)(qb + rg * 16 + c) * 256;
    #pragma unroll
    for (int ks = 0; ks < 8; ++ks) {
        int k0 = ks * 32 + g * 8;
        float4 s0 = *(const float4*)(srow + k0);
        float4 s1 = *(const float4*)(srow + k0 + 4);
        bf16x8 af;
        af[0] = (short)f2bf(s0.x); af[1] = (short)f2bf(s0.y);
        af[2] = (short)f2bf(s0.z); af[3] = (short)f2bf(s0.w);
        af[4] = (short)f2bf(s1.x); af[5] = (short)f2bf(s1.y);
        af[6] = (short)f2bf(s1.z); af[7] = (short)f2bf(s1.w);
        #pragma unroll
        for (int ob = 0; ob < 2; ++ob) {
            int brow = oh * 32 + ob * 16 + c;
            bf16x8 bf = *(const bf16x8*)(&w1t[brow * 264 + k0]);
            acc[ob] = __builtin_amdgcn_mfma_f32_16x16x32_bf16(af, bf, acc[ob], 0, 0, 0);
        }
    }

    // f1/f2 partial: rows of C are g*4+reg (local), cols oh*32+ob*16+c
    float a1v0 = a1[oh * 32 + c], a1v1 = a1[oh * 32 + 16 + c];
    float a2v0 = a2[oh * 32 + c], a2v1 = a2[oh * 32 + 16 + c];
    #pragma unroll
    for (int reg = 0; reg < 4; ++reg) {
        float p1 = acc[0][reg] * a1v0 + acc[1][reg] * a1v1;
        float p2 = acc[0][reg] * a2v0 + acc[1][reg] * a2v1;
        #pragma unroll
        for (int mm = 1; mm < 16; mm <<= 1) {
            p1 += __shfl_xor(p1, mm, 64);
            p2 += __shfl_xor(p2, mm, 64);
        }
        if (c == 0) {
            f1p[oh][rg * 16 + g * 4 + reg] = p1;
            f2p[oh][rg * 16 + g * 4 + reg] = p2;
        }
    }

    // stage fts^T bf16: stage[o][q_local], o = oh*32+ob*16+c, q = rg*16+g*4+reg
    #pragma unroll
    for (int ob = 0; ob < 2; ++ob) {
        int row = oh * 32 + ob * 16 + c;
        #pragma unroll
        for (int rp = 0; rp < 2; ++rp) {
            unsigned short lo = f2bf(acc[ob][rp * 2]);
            unsigned short hi = f2bf(acc[ob][rp * 2 + 1]);
            unsigned v = (unsigned)lo | ((unsigned)hi << 16);
            *(unsigned*)(&stage[row * 40 + rg * 16 + g * 4 + rp * 2]) = v;
        }
    }
    __syncthreads();

    // coalesced copy stage -> ftsT[o][qb..qb+31]
    {
        int o = tid >> 2, q4 = tid & 3;
        uint4 v = *(const uint4*)(&stage[o * 40 + q4 * 8]);
        *(uint4*)(&ftsT[(long)o * 8192 + qb + q4 * 8]) = v;
    }
    if (tid < 32) {
        f1g[qb + tid] = f1p[0][tid] + f1p[1][tid] + b1[0];
        f2g[qb + tid] = f2p[0][tid] + f2p[1][tid] + b2[0];
    }
}

// ---------------- kernel B: online-softmax attention ----------------
// grid 256, block 512 (8 waves). Block = 32 q-rows; wave w: rg=w&1 (16-row
// half), h=w>>1 (4-way j split). Round = 128 j, 64 rounds, double-buffered
// LDS with register prefetch one round ahead (T14).
__global__ __launch_bounds__(512) void attn_main(
    const float* __restrict__ bias, const unsigned short* __restrict__ ftsT,
    const float* __restrict__ f1g, const float* __restrict__ f2g,
    float* __restrict__ out)
{
    __shared__ float bias_lds[2][32][132];          // 33.8 KB, 528B rows (16B-aligned, odd*16)
    __shared__ unsigned short fts_lds[2][64][136];  // 34.8 KB, 272B rows
    __shared__ float macc[2][4][16][68];            // merge area 34.8 KB
    __shared__ float mlm[2][4][16];
    __shared__ float mll[2][4][16];

    const int tid = threadIdx.x;
    const int qb = blockIdx.x * 32;
    const int w = tid >> 6, rg = w & 1, h = w >> 1;
    const int lane = tid & 63, c = lane & 15, g = lane >> 4;

    // staging roles
    const int srow = tid >> 4;            // 0..31 bias row
    const int ssub = tid & 15;            // 32B chunk within 512B row
    const long brow_base = (long)(qb + srow) * 8192;
    const int frow = tid >> 3;            // 0..63 ftsT row
    const int fchunk = tid & 7;           // 32B chunk within 256B row

    const float f1r = f1g[qb + rg * 16 + c];

    float4 pb0, pb1, pf2a, pf2b;
    uint4 pf0, pf1;
    {   // prefetch round 0
        const float* bp = bias + brow_base + ssub * 8;
        pb0 = ((const float4*)bp)[0];
        pb1 = ((const float4*)bp)[1];
        const unsigned short* fp = ftsT + (long)frow * 8192 + fchunk * 16;
        pf0 = ((const uint4*)fp)[0];
        pf1 = ((const uint4*)fp)[1];
        const float* f2p_ = f2g + h * 32 + g * 8;
        pf2a = ((const float4*)f2p_)[0];
        pf2b = ((const float4*)f2p_)[1];
    }

    float m = -INFINITY, lsum = 0.f;
    f32x4 acc[4] = {};

    for (int r = 0; r < 64; ++r) {
        const int buf = r & 1;
        __syncthreads();
        // commit prefetched round r to LDS
        *(float4*)(&bias_lds[buf][srow][ssub * 8]) = pb0;
        *(float4*)(&bias_lds[buf][srow][ssub * 8 + 4]) = pb1;
        *(uint4*)(&fts_lds[buf][frow][fchunk * 16]) = pf0;
        *(uint4*)(&fts_lds[buf][frow][fchunk * 16 + 8]) = pf1;
        float f2v[8];
        f2v[0] = pf2a.x; f2v[1] = pf2a.y; f2v[2] = pf2a.z; f2v[3] = pf2a.w;
        f2v[4] = pf2b.x; f2v[5] = pf2b.y; f2v[6] = pf2b.z; f2v[7] = pf2b.w;
        // issue loads for round r+1 (in flight across compute below)
        if (r + 1 < 64) {
            const int j0 = (r + 1) * 128;
            const float* bp = bias + brow_base + j0 + ssub * 8;
            pb0 = ((const float4*)bp)[0];
            pb1 = ((const float4*)bp)[1];
            const unsigned short* fp = ftsT + (long)frow * 8192 + j0 + fchunk * 16;
            pf0 = ((const uint4*)fp)[0];
            pf1 = ((const uint4*)fp)[1];
            const float* f2p_ = f2g + j0 + h * 32 + g * 8;
            pf2a = ((const float4*)f2p_)[0];
            pf2b = ((const float4*)f2p_)[1];
        }
        __syncthreads();

        // S for 16 rows x 32 j (this wave): lane holds row c, j = h*32+g*8+i
        float4 s0 = *(const float4*)(&bias_lds[buf][rg * 16 + c][h * 32 + g * 8]);
        float4 s1 = *(const float4*)(&bias_lds[buf][rg * 16 + c][h * 32 + g * 8 + 4]);
        float bb[8] = { s0.x, s0.y, s0.z, s0.w, s1.x, s1.y, s1.z, s1.w };
        float s[8];
        float tm = -INFINITY;
        #pragma unroll
        for (int i = 0; i < 8; ++i) {
            float z = f1r + f2v[i];
            z = fmaxf(z, 0.2f * z);          // leaky_relu(0.2)
            float sv = z + bb[i];
            s[i] = sv;
            tm = fmaxf(tm, sv);
        }
        tm = fmaxf(tm, __shfl_xor(tm, 16, 64));
        tm = fmaxf(tm, __shfl_xor(tm, 32, 64));
        const float mnew = fmaxf(m, tm);
        const float sc = __expf(m - mnew);
        float ts = 0.f;
        bf16x8 af;
        #pragma unroll
        for (int i = 0; i < 8; ++i) {
            float p = __expf(s[i] - mnew);
            ts += p;
            af[i] = (short)f2bf(p);
        }
        ts += __shfl_xor(ts, 16, 64);
        ts += __shfl_xor(ts, 32, 64);
        lsum = lsum * sc + ts;
        m = mnew;
        // rescale acc: C rows are g*4+reg; row q's scale lives in lane q (q<16)
        float scq[4];
        #pragma unroll
        for (int reg = 0; reg < 4; ++reg) scq[reg] = __shfl(sc, g * 4 + reg, 64);
        #pragma unroll
        for (int ob = 0; ob < 4; ++ob) {
            #pragma unroll
            for (int reg = 0; reg < 4; ++reg) acc[ob][reg] *= scq[reg];
        }
        // PV: A = P (16x32), B = fts (32 j x 16 o) from ftsT rows
        #pragma unroll
        for (int ob = 0; ob < 4; ++ob) {
            bf16x8 bfrag = *(const bf16x8*)(&fts_lds[buf][ob * 16 + c][h * 32 + g * 8]);
            acc[ob] = __builtin_amdgcn_mfma_f32_16x16x32_bf16(af, bfrag, acc[ob], 0, 0, 0);
        }
    }

    __syncthreads();
    // dump per-wave partial state
    #pragma unroll
    for (int ob = 0; ob < 4; ++ob) {
        #pragma unroll
        for (int reg = 0; reg < 4; ++reg)
            macc[rg][h][g * 4 + reg][ob * 16 + c] = acc[ob][reg];
    }
    if (lane < 16) { mlm[rg][h][c] = m; mll[rg][h][c] = lsum; }
    __syncthreads();

    // merge 4 j-splits, normalize, elu, store. 512 thr x 4 outputs.
    {
        const int row = tid >> 4;            // 0..31
        const int o0 = (tid & 15) * 4;
        const int rg2 = row >> 4, rr = row & 15;
        float m0 = mlm[rg2][0][rr], m1 = mlm[rg2][1][rr];
        float m2 = mlm[rg2][2][rr], m3 = mlm[rg2][3][rr];
        float ms = fmaxf(fmaxf(m0, m1), fmaxf(m2, m3));
        float w0 = __expf(m0 - ms), w1 = __expf(m1 - ms);
        float w2 = __expf(m2 - ms), w3 = __expf(m3 - ms);
        float den = mll[rg2][0][rr] * w0 + mll[rg2][1][rr] * w1 +
                    mll[rg2][2][rr] * w2 + mll[rg2][3][rr] * w3;
        float inv = 1.f / den;
        float4 v0 = *(const float4*)(&macc[rg2][0][rr][o0]);
        float4 v1 = *(const float4*)(&macc[rg2][1][rr][o0]);
        float4 v2 = *(const float4*)(&macc[rg2][2][rr][o0]);
        float4 v3 = *(const float4*)(&macc[rg2][3][rr][o0]);
        float4 res;
        res.x = elu1((v0.x * w0 + v1.x * w1 + v2.x * w2 + v3.x * w3) * inv);
        res.y = elu1((v0.y * w0 + v1.y * w1 + v2.y * w2 + v3.y * w3) * inv);
        res.z = elu1((v0.z * w0 + v1.z * w1 + v2.z * w2 + v3.z * w3) * inv);
        res.w = elu1((v0.w * w0 + v1.w * w1 + v2.w * w2 + v3.w * w3) * inv);
        *(float4*)(&out[(long)(qb + row) * 64 + o0]) = res;
    }
}

extern "C" void kernel_launch(void* const* d_in, const int* in_sizes, int n_in,
                              void* d_out, int out_size, void* d_ws, size_t ws_size,
                              hipStream_t stream) {
    (void)in_sizes; (void)n_in; (void)out_size; (void)ws_size;
    const float* seq  = (const float*)d_in[0];
    const float* bias = (const float*)d_in[1];
    const float* W1   = (const float*)d_in[2];
    const float* a1   = (const float*)d_in[3];
    const float* b1   = (const float*)d_in[4];
    const float* a2   = (const float*)d_in[5];
    const float* b2   = (const float*)d_in[6];
    float* out = (float*)d_out;

    unsigned short* ftsT = (unsigned short*)d_ws;                      // 64*8192*2 = 1 MB
    float* f1 = (float*)((char*)d_ws + 64 * 8192 * 2);                 // 32 KB
    float* f2 = (float*)((char*)d_ws + 64 * 8192 * 2 + 8192 * 4);      // 32 KB

    hipLaunchKernelGGL(attn_fts, dim3(256), dim3(256), 0, stream,
                       seq, W1, a1, b1, a2, b2, ftsT, f1, f2);
    hipLaunchKernelGGL(attn_main, dim3(256), dim3(512), 0, stream,
                       bias, ftsT, f1, f2, out);
}